// Round 5
// baseline (385.039 us; speedup 1.0000x reference)
//
#include <hip/hip_runtime.h>
#include <stdint.h>

typedef __attribute__((ext_vector_type(4))) int v4i;    // 16 int8 (A/B frag) or 4 int32 (acc)

__device__ inline void load_lds16(const void* g, void* l) {
  // async global->LDS, 16B/lane. LDS dest must be wave-uniform base + lane*16.
  __builtin_amdgcn_global_load_lds(
      (const __attribute__((address_space(1))) uint32_t*)g,
      (__attribute__((address_space(3))) uint32_t*)l, 16, 0, 0);
}

// ---------- fused prep: activation quant (blocks 0..M-1) + weight repack ----
// Non-gemm residue measured ~249us across 3 structurally different prep
// configs (R0-R4) => ~210us is fixed harness overhead; prep is ~40us of HBM
// traffic and already coalesced. Do not over-engineer this kernel.
__global__ __launch_bounds__(256)
void prep_kernel(const float* __restrict__ in, int8_t* __restrict__ aq,
                 float* __restrict__ rscale, int K, int Mrows,
                 const void* __restrict__ wraw, int8_t* __restrict__ wq) {
  const int tid = threadIdx.x;

  if ((int)blockIdx.x < Mrows) {
    // ---- activation quant path ----
    const int row = blockIdx.x;
    __shared__ float s_part[4];
    __shared__ float s_inv;
    const float4* p = (const float4*)(in + (size_t)row * K);
    float4 v[4];
    float amax = 0.f;
#pragma unroll
    for (int j = 0; j < 4; ++j) {
      v[j] = p[tid + 256 * j];
      amax = fmaxf(amax, fmaxf(fmaxf(fabsf(v[j].x), fabsf(v[j].y)),
                               fmaxf(fabsf(v[j].z), fabsf(v[j].w))));
    }
#pragma unroll
    for (int off = 32; off > 0; off >>= 1)
      amax = fmaxf(amax, __shfl_down(amax, off));
    if ((tid & 63) == 0) s_part[tid >> 6] = amax;
    __syncthreads();
    if (tid == 0) {
      float m = fmaxf(fmaxf(s_part[0], s_part[1]), fmaxf(s_part[2], s_part[3]));
      s_inv = (m > 0.f) ? 127.f / m : 0.f;
      rscale[row] = (m > 0.f) ? m / 127.f : 0.f;
    }
    __syncthreads();
    const float inv = s_inv;
    uint32_t* o32 = (uint32_t*)(aq + (size_t)row * K);
#pragma unroll
    for (int j = 0; j < 4; ++j) {
      float f[4] = {v[j].x, v[j].y, v[j].z, v[j].w};
      uint32_t b = 0;
#pragma unroll
      for (int t = 0; t < 4; ++t) {
        int q = (int)rintf(f[t] * inv);
        q = q > 127 ? 127 : (q < -127 ? -127 : q);
        b |= ((uint32_t)q & 0xffu) << (8 * t);
      }
      o32[tid + 256 * j] = b;
    }
  } else {
    // ---- weight repack path: output word i = 4 int8 weights ----
    const int i = (blockIdx.x - Mrows) * 256 + tid;
    const int4 a = ((const int4*)wraw)[i];
    int ok = 1;
#pragma unroll
    for (int t = 0; t < 4; ++t) {
      uint32_t v = (uint32_t)(t == 0 ? a.x : t == 1 ? a.y : t == 2 ? a.z : a.w);
      uint32_t expect = (v & 0x80u) ? 0xFFFFFFu : 0u;
      if ((v >> 8) != expect) ok = 0;
    }
    if (__syncthreads_and(ok)) {   // block-uniform verdict over its 4096 words
      uint32_t b = ((uint32_t)a.x & 0xffu) | (((uint32_t)a.y & 0xffu) << 8) |
                   (((uint32_t)a.z & 0xffu) << 16) | (((uint32_t)a.w & 0xffu) << 24);
      ((uint32_t*)wq)[i] = b;
    } else {                        // already-packed int8: plain copy
      ((uint32_t*)wq)[i] = ((const uint32_t*)wraw)[i];
    }
  }
}

// ---------- int8 GEMM: 16x16x64, 8-phase counted-vmcnt, A-frag pipelining ---
// C = A * B^T, 256x256 tile, int32 exact acc, fused dequant epilogue.
//
// R4 cycle model (fits measured 5006 cy/K-tile to 6%): lockstep barriers
// serialize each phase's ds_read burst with the MFMA block. Fix: A-fragment
// reads are pipelined ONE PHASE AHEAD into a double-buffered register set
// (afA/afB, statically named), issued inside the MFMA region so they overlap
// compute. Cross-buffer prefetches (ph4: A1, ph8: A0-next) sit after that
// phase's VMW+barrier, so buffer retirement still precedes every read:
//   ph1-2 STG A1<-t1 | ph3-4 STG B0<-t2 | VMW@ph4 retires {A1-t1, B1-t1}
//   ph5-6 STG A0<-t2 | ph7-8 STG B1<-t3 | VMW@ph8 retires {B0-t2, A0-t2}
// B-frag bursts stay at ph1/ph5 top (their buffers retire only at the
// immediately preceding VMW); [0]-half loaded first so the compiler's
// fine-grained lgkmcnt releases the first MFMA octet before the [1]s land.
//
// LDS swizzle: (row r, 16B-chunk c) at chunk c^(r&7); fragment pattern
// chunk=(l>>4)^(l&7) measured conflict-free (R1/R4: SQ_LDS_BANK_CONFLICT=0).
// The 32x32 (l>>5) pattern measured 1.26e7 conflicts — do not "upgrade".
__global__ __launch_bounds__(512, 2)
void gemm_i8_8ph(const int8_t* __restrict__ A, const int8_t* __restrict__ B,
                 const float* __restrict__ ascale, const float* __restrict__ scale,
                 const float* __restrict__ bias, float* __restrict__ C,
                 int Mdim, int Ndim, int Kdim) {
  __shared__ __align__(16) int8_t sm[131072];
  int8_t* const sA0 = sm;
  int8_t* const sA1 = sm + 32768;
  int8_t* const sB0 = sm + 65536;
  int8_t* const sB1 = sm + 98304;

  const int tid  = threadIdx.x;
  const int lane = tid & 63;
  const int wave = tid >> 6;
  const int wm = (wave >> 2) * 128;   // 2 M-waves x 4 N-waves, 128x64 per wave
  const int wn = (wave & 3) * 64;

  // T1: XCD-aware bijective swizzle (grid % 8 == 0 guaranteed by launcher)
  const int nwg = gridDim.x;
  const int cpx = nwg >> 3;
  const int bid = blockIdx.x;
  const int swz = (bid & 7) * cpx + (bid >> 3);
  const int nbn = Ndim >> 8;          // N/256
  const int bm = swz / nbn, bn = swz % nbn;

  const int NT = Kdim >> 7;           // K-tiles of 128
  const int NI = NT >> 1;

  // staging source: thread -> (row s8 within 64-row group, swizzled 16B chunk)
  const int s8   = tid >> 3;
  const int scol = ((tid & 7) ^ (s8 & 7)) << 4;
  const int8_t* gA = A + (size_t)(bm * 256 + s8) * Kdim + scol;
  const int8_t* gB = B + (size_t)(bn * 256 + s8) * Kdim + scol;
  const size_t rstep = (size_t)64 * Kdim;
  const int dst16 = tid << 4;

  // fragment read offsets: row = (wm|wn) + f*16 + frow, k-chunk (ks*4+g)^(frow&7)
  const int frow = lane & 15;
  const int g    = lane >> 4;
  const int f7   = frow & 7;
  const int pc0  = ((g) ^ f7) << 4;
  const int pc1  = ((4 + g) ^ f7) << 4;
  const int aro  = (wm + frow) << 7;
  const int bro  = (wn + frow) << 7;

  v4i acc[8][4];
#pragma unroll
  for (int mi = 0; mi < 8; ++mi)
#pragma unroll
    for (int ni = 0; ni < 4; ++ni) acc[mi][ni] = (v4i){0, 0, 0, 0};

  // A-fragment double buffer: afX holds m-pair frags {a(2m,kc0), a(2m,kc1),
  // a(2m+1,kc0), a(2m+1,kc1)}. Lives across iterations (ph8 preloads next ph1).
  v4i afA[4], afB[4];

#define STG(DST_, GS_, T_, RG_) \
  load_lds16(GS_ + (size_t)(RG_) * rstep + ((size_t)(T_) << 7), DST_ + ((RG_) << 13) + dst16)

#define LDA(DST_, SA_, m_)                                                  \
  DST_[0] = *(const v4i*)((SA_) + aro + (2 * (m_)) * 2048 + pc0);           \
  DST_[1] = *(const v4i*)((SA_) + aro + (2 * (m_)) * 2048 + pc1);           \
  DST_[2] = *(const v4i*)((SA_) + aro + (2 * (m_) + 1) * 2048 + pc0);       \
  DST_[3] = *(const v4i*)((SA_) + aro + (2 * (m_) + 1) * 2048 + pc1);

  // prologue: B(0)->B0, A(0)->A0, B(1)->B1; wait tile0 (leave B(1)'s 4 in flight)
  STG(sB0, gB, 0, 0); STG(sB0, gB, 0, 1); STG(sB0, gB, 0, 2); STG(sB0, gB, 0, 3);
  STG(sA0, gA, 0, 0); STG(sA0, gA, 0, 1); STG(sA0, gA, 0, 2); STG(sA0, gA, 0, 3);
  STG(sB1, gB, 1, 0); STG(sB1, gB, 1, 1); STG(sB1, gB, 1, 2); STG(sB1, gB, 1, 3);
  asm volatile("s_waitcnt vmcnt(4)" ::: "memory");
  __builtin_amdgcn_s_barrier();
  __builtin_amdgcn_sched_barrier(0);
  LDA(afA, sA0, 0);   // preload ph1's m-pair 0 (sA0-t0 retired above)

#define VMW asm volatile("s_waitcnt vmcnt(4)" ::: "memory")

  // Phase: [bf burst if LOADB] + 2 STG + [VMW] -> barrier -> setprio ->
  //        {prefetch next m-pair into AFN_ (interleaves with MFMA)} +
  //        16 MFMA on AF_ -> barrier.
#define PH(AF_, AFN_, SAN_, mn_, SB_, q_, LOADB_, S1_, S2_, VM_)                              \
  {                                                                                           \
    if (LOADB_) {                                                                             \
      _Pragma("unroll") for (int ni = 0; ni < 4; ++ni)                                        \
        bf[ni][0] = *(const v4i*)((SB_) + bro + ni * 2048 + pc0);                             \
      _Pragma("unroll") for (int ni = 0; ni < 4; ++ni)                                        \
        bf[ni][1] = *(const v4i*)((SB_) + bro + ni * 2048 + pc1);                             \
    }                                                                                         \
    S1_; S2_; VM_;                                                                            \
    __builtin_amdgcn_s_barrier();                                                             \
    __builtin_amdgcn_s_setprio(1);                                                            \
    LDA(AFN_, SAN_, mn_);                                                                     \
    _Pragma("unroll") for (int ni = 0; ni < 4; ++ni) {                                        \
      acc[2*(q_)][ni]   = __builtin_amdgcn_mfma_i32_16x16x64_i8(AF_[0], bf[ni][0], acc[2*(q_)][ni], 0, 0, 0);   \
      acc[2*(q_)+1][ni] = __builtin_amdgcn_mfma_i32_16x16x64_i8(AF_[2], bf[ni][0], acc[2*(q_)+1][ni], 0, 0, 0); \
    }                                                                                         \
    _Pragma("unroll") for (int ni = 0; ni < 4; ++ni) {                                        \
      acc[2*(q_)][ni]   = __builtin_amdgcn_mfma_i32_16x16x64_i8(AF_[1], bf[ni][1], acc[2*(q_)][ni], 0, 0, 0);   \
      acc[2*(q_)+1][ni] = __builtin_amdgcn_mfma_i32_16x16x64_i8(AF_[3], bf[ni][1], acc[2*(q_)+1][ni], 0, 0, 0); \
    }                                                                                         \
    __builtin_amdgcn_s_setprio(0);                                                            \
    __builtin_amdgcn_sched_barrier(0);                                                        \
    __builtin_amdgcn_s_barrier();                                                             \
    __builtin_amdgcn_sched_barrier(0);                                                        \
  }

#pragma unroll 1
  for (int i = 0; i < NI; ++i) {
    v4i bf[4][2];
    const int t1 = 2 * i + 1;
    int t2 = 2 * i + 2; if (t2 >= NT) t2 -= NT;   // tail clamp: redundant but safe
    int t3 = 2 * i + 3; if (t3 >= NT) t3 -= NT;
    // AF_ consumed / AFN_ preloaded alternate; ph4 prefetches from sA1 (retired
    // by ph4's VMW, read after its barrier); ph8 from sA0 (retired by ph8 VMW).
    PH(afA, afB, sA0, 1, sB0, 0, 1, STG(sA1, gA, t1, 0), STG(sA1, gA, t1, 1), (void)0);
    PH(afB, afA, sA0, 2, sB0, 1, 0, STG(sA1, gA, t1, 2), STG(sA1, gA, t1, 3), (void)0);
    PH(afA, afB, sA0, 3, sB0, 2, 0, STG(sB0, gB, t2, 0), STG(sB0, gB, t2, 1), (void)0);
    PH(afB, afA, sA1, 0, sB0, 3, 0, STG(sB0, gB, t2, 2), STG(sB0, gB, t2, 3), VMW);
    PH(afA, afB, sA1, 1, sB1, 0, 1, STG(sA0, gA, t2, 0), STG(sA0, gA, t2, 1), (void)0);
    PH(afB, afA, sA1, 2, sB1, 1, 0, STG(sA0, gA, t2, 2), STG(sA0, gA, t2, 3), (void)0);
    PH(afA, afB, sA1, 3, sB1, 2, 0, STG(sB1, gB, t3, 0), STG(sB1, gB, t3, 1), (void)0);
    PH(afB, afA, sA0, 0, sB1, 3, 0, STG(sB1, gB, t3, 2), STG(sB1, gB, t3, 3), VMW);
  }
  // drain in-flight LDS writes before endpgm (LDS may be re-allocated)
  asm volatile("s_waitcnt vmcnt(0)" ::: "memory");

  // epilogue: C/D layout col=lane&15, row=(lane>>4)*4+reg (shape-determined).
  const int col0 = bn * 256 + wn + (lane & 15);
  const int row0 = bm * 256 + wm + ((lane >> 4) << 2);
  float scv[4], bsv[4];
#pragma unroll
  for (int ni = 0; ni < 4; ++ni) {
    scv[ni] = scale[col0 + ni * 16];
    bsv[ni] = bias[col0 + ni * 16];
  }
#pragma unroll
  for (int mi = 0; mi < 8; ++mi) {
#pragma unroll
    for (int r = 0; r < 4; ++r) {
      const int row = row0 + mi * 16 + r;
      const float as = ascale[row];
      float* crow = C + (size_t)row * Ndim;
#pragma unroll
      for (int ni = 0; ni < 4; ++ni)
        crow[col0 + ni * 16] = (float)acc[mi][ni][r] * as * scv[ni] + bsv[ni];
    }
  }
#undef PH
#undef VMW
#undef LDA
#undef STG
}

// ---------- safety-net naive kernel (only if ws too small / odd shapes) -----
__global__ void naive_kernel(const float* __restrict__ A, const int* __restrict__ W,
                             const float* __restrict__ scale, const float* __restrict__ bias,
                             float* __restrict__ C, int Mdim, int Ndim, int Kdim) {
  int idx = blockIdx.x * blockDim.x + threadIdx.x;
  if (idx >= Mdim * Ndim) return;
  int row = idx / Ndim, col = idx % Ndim;
  const float* a = A + (size_t)row * Kdim;
  const int* w = W + (size_t)col * Kdim;
  float s = 0.f;
  for (int k = 0; k < Kdim; ++k) s += a[k] * (float)w[k];
  C[idx] = s * scale[col] + bias[col];
}

extern "C" void kernel_launch(void* const* d_in, const int* in_sizes, int n_in,
                              void* d_out, int out_size, void* d_ws, size_t ws_size,
                              hipStream_t stream) {
  const float* inp   = (const float*)d_in[0];
  const void*  w_raw = d_in[1];                 // int32 carrier (per harness) or int8
  const float* scale = (const float*)d_in[2];
  const float* bias  = (const float*)d_in[3];
  float* out = (float*)d_out;

  const int N = in_sizes[2];          // 4096 (D_OUT)
  const int K = in_sizes[1] / N;      // 4096 (D_IN)
  const int M = in_sizes[0] / K;      // 8192 (B*S)

  size_t needA = (size_t)M * K;              // int8 A
  size_t needW = (size_t)N * K;              // int8 W
  size_t needS = (size_t)M * sizeof(float);  // per-row scales
  size_t need  = needA + needW + needS + 16;

  const int nblk = (M / 256) * (N / 256);
  if (ws_size < need || (M % 256) || (N % 256) || (K != 4096) || (nblk % 8)) {
    int total = M * N;   // safety net — should not trigger for harness shapes
    naive_kernel<<<(total + 255) / 256, 256, 0, stream>>>(
        inp, (const int*)w_raw, scale, bias, out, M, N, K);
    return;
  }

  int8_t* Aq = (int8_t*)d_ws;
  int8_t* Wq = Aq + needA;
  float* ascale = (float*)(Wq + needW);

  // single fused prep launch: quant rows (blocks 0..M-1) + weight repack
  const int n4 = (N * K) / 4;
  const int repack_blocks = n4 / 256;
  prep_kernel<<<M + repack_blocks, 256, 0, stream>>>(inp, Aq, ascale, K, M,
                                                     w_raw, Wq);

  gemm_i8_8ph<<<nblk, 512, 0, stream>>>(Aq, Wq, ascale, scale, bias, out, M, N, K);
}

// Round 6
// 376.042 us; speedup vs baseline: 1.0239x; 1.0239x over previous
//
#include <hip/hip_runtime.h>
#include <stdint.h>

typedef __attribute__((ext_vector_type(4))) int v4i;    // 16 int8 (A/B frag) or 4 int32 (acc)

__device__ inline void load_lds16(const void* g, void* l) {
  // async global->LDS, 16B/lane. LDS dest must be wave-uniform base + lane*16.
  __builtin_amdgcn_global_load_lds(
      (const __attribute__((address_space(1))) uint32_t*)g,
      (__attribute__((address_space(3))) uint32_t*)l, 16, 0, 0);
}

// ---------- fused prep: activation quant (blocks 0..M-1) + weight repack ----
// Non-gemm residue measured ~249us across 3 structurally different prep
// configs (R0-R4) => ~210us is fixed harness overhead; prep is ~40us of HBM
// traffic and already coalesced. Do not over-engineer this kernel.
__global__ __launch_bounds__(256)
void prep_kernel(const float* __restrict__ in, int8_t* __restrict__ aq,
                 float* __restrict__ rscale, int K, int Mrows,
                 const void* __restrict__ wraw, int8_t* __restrict__ wq) {
  const int tid = threadIdx.x;

  if ((int)blockIdx.x < Mrows) {
    // ---- activation quant path ----
    const int row = blockIdx.x;
    __shared__ float s_part[4];
    __shared__ float s_inv;
    const float4* p = (const float4*)(in + (size_t)row * K);
    float4 v[4];
    float amax = 0.f;
#pragma unroll
    for (int j = 0; j < 4; ++j) {
      v[j] = p[tid + 256 * j];
      amax = fmaxf(amax, fmaxf(fmaxf(fabsf(v[j].x), fabsf(v[j].y)),
                               fmaxf(fabsf(v[j].z), fabsf(v[j].w))));
    }
#pragma unroll
    for (int off = 32; off > 0; off >>= 1)
      amax = fmaxf(amax, __shfl_down(amax, off));
    if ((tid & 63) == 0) s_part[tid >> 6] = amax;
    __syncthreads();
    if (tid == 0) {
      float m = fmaxf(fmaxf(s_part[0], s_part[1]), fmaxf(s_part[2], s_part[3]));
      s_inv = (m > 0.f) ? 127.f / m : 0.f;
      rscale[row] = (m > 0.f) ? m / 127.f : 0.f;
    }
    __syncthreads();
    const float inv = s_inv;
    uint32_t* o32 = (uint32_t*)(aq + (size_t)row * K);
#pragma unroll
    for (int j = 0; j < 4; ++j) {
      float f[4] = {v[j].x, v[j].y, v[j].z, v[j].w};
      uint32_t b = 0;
#pragma unroll
      for (int t = 0; t < 4; ++t) {
        int q = (int)rintf(f[t] * inv);
        q = q > 127 ? 127 : (q < -127 ? -127 : q);
        b |= ((uint32_t)q & 0xffu) << (8 * t);
      }
      o32[tid + 256 * j] = b;
    }
  } else {
    // ---- weight repack path: output word i = 4 int8 weights ----
    const int i = (blockIdx.x - Mrows) * 256 + tid;
    const int4 a = ((const int4*)wraw)[i];
    int ok = 1;
#pragma unroll
    for (int t = 0; t < 4; ++t) {
      uint32_t v = (uint32_t)(t == 0 ? a.x : t == 1 ? a.y : t == 2 ? a.z : a.w);
      uint32_t expect = (v & 0x80u) ? 0xFFFFFFu : 0u;
      if ((v >> 8) != expect) ok = 0;
    }
    if (__syncthreads_and(ok)) {   // block-uniform verdict over its 4096 words
      uint32_t b = ((uint32_t)a.x & 0xffu) | (((uint32_t)a.y & 0xffu) << 8) |
                   (((uint32_t)a.z & 0xffu) << 16) | (((uint32_t)a.w & 0xffu) << 24);
      ((uint32_t*)wq)[i] = b;
    } else {                        // already-packed int8: plain copy
      ((uint32_t*)wq)[i] = ((const uint32_t*)wraw)[i];
    }
  }
}

// ---------- int8 GEMM: 16x16x64, 8-phase counted-vmcnt, SINGLE barrier/phase
// C = A * B^T, 256x256 tile, int32 exact acc, fused dequant epilogue.
//
// R4 model (fits measured 5006 cy/K-tile): MFMA 2611 cy + ds_read port 2304 cy,
// fully serialized because TWO barriers/phase lockstep all 8 waves: reads
// together (matrix idle), MFMA together (LDS idle). R5 showed intra-wave read
// prefetch doesn't help (compiler already overlaps reads with the barrier
// wait). This version removes the post-MFMA barrier (barB): one barrier per
// phase. Dependency audit (why barB is dead):
//  - writer->reader: every buffer's STGs are retired by a VMW and published by
//    the barrier that FOLLOWS the VMW (barA of ph4/ph8) before any read.
//  - reader->next-writer: phase q's reads precede barA(q); the next STG to that
//    buffer is issued at phase q+1, i.e. after barA(q) -> no WAR race.
// With one barrier/phase, matrix-pipe contention skews the 2 waves/SIMD so an
// early-finishing wave runs its next-phase ds_reads under its mate's MFMAs.
//
// Ledger (unchanged, per-wave):
//   ph1-2 STG A1<-t1 | ph3-4 STG B0<-t2 | VMW@ph4 retires {A1-t1, B1-t1}
//   ph5-6 STG A0<-t2 | ph7-8 STG B1<-t3 | VMW@ph8 retires {B0-t2, A0-t2}
//
// LDS swizzle: (row r, 16B-chunk c) at chunk c^(r&7); fragment pattern
// chunk=(l>>4)^(l&7) measured conflict-free (R1/R4: SQ_LDS_BANK_CONFLICT=0).
// The 32x32 (l>>5) pattern measured 1.26e7 conflicts — do not "upgrade".
__global__ __launch_bounds__(512, 2)
void gemm_i8_8ph(const int8_t* __restrict__ A, const int8_t* __restrict__ B,
                 const float* __restrict__ ascale, const float* __restrict__ scale,
                 const float* __restrict__ bias, float* __restrict__ C,
                 int Mdim, int Ndim, int Kdim) {
  __shared__ __align__(16) int8_t sm[131072];
  int8_t* const sA0 = sm;
  int8_t* const sA1 = sm + 32768;
  int8_t* const sB0 = sm + 65536;
  int8_t* const sB1 = sm + 98304;

  const int tid  = threadIdx.x;
  const int lane = tid & 63;
  const int wave = tid >> 6;
  const int wm = (wave >> 2) * 128;   // 2 M-waves x 4 N-waves, 128x64 per wave
  const int wn = (wave & 3) * 64;

  // T1: XCD-aware bijective swizzle (grid % 8 == 0 guaranteed by launcher)
  const int nwg = gridDim.x;
  const int cpx = nwg >> 3;
  const int bid = blockIdx.x;
  const int swz = (bid & 7) * cpx + (bid >> 3);
  const int nbn = Ndim >> 8;          // N/256
  const int bm = swz / nbn, bn = swz % nbn;

  const int NT = Kdim >> 7;           // K-tiles of 128
  const int NI = NT >> 1;

  // staging source: thread -> (row s8 within 64-row group, swizzled 16B chunk)
  const int s8   = tid >> 3;
  const int scol = ((tid & 7) ^ (s8 & 7)) << 4;
  const int8_t* gA = A + (size_t)(bm * 256 + s8) * Kdim + scol;
  const int8_t* gB = B + (size_t)(bn * 256 + s8) * Kdim + scol;
  const size_t rstep = (size_t)64 * Kdim;
  const int dst16 = tid << 4;

  // fragment read offsets: row = (wm|wn) + f*16 + frow, k-chunk (ks*4+g)^(frow&7)
  const int frow = lane & 15;
  const int g    = lane >> 4;
  const int f7   = frow & 7;
  const int pc0  = ((g) ^ f7) << 4;
  const int pc1  = ((4 + g) ^ f7) << 4;
  const int aro  = (wm + frow) << 7;
  const int bro  = (wn + frow) << 7;

  v4i acc[8][4];
#pragma unroll
  for (int mi = 0; mi < 8; ++mi)
#pragma unroll
    for (int ni = 0; ni < 4; ++ni) acc[mi][ni] = (v4i){0, 0, 0, 0};

#define STG(DST_, GS_, T_, RG_) \
  load_lds16(GS_ + (size_t)(RG_) * rstep + ((size_t)(T_) << 7), DST_ + ((RG_) << 13) + dst16)

  // prologue: B(0)->B0, A(0)->A0, B(1)->B1; wait tile0 (leave B(1)'s 4 in flight)
  STG(sB0, gB, 0, 0); STG(sB0, gB, 0, 1); STG(sB0, gB, 0, 2); STG(sB0, gB, 0, 3);
  STG(sA0, gA, 0, 0); STG(sA0, gA, 0, 1); STG(sA0, gA, 0, 2); STG(sA0, gA, 0, 3);
  STG(sB1, gB, 1, 0); STG(sB1, gB, 1, 1); STG(sB1, gB, 1, 2); STG(sB1, gB, 1, 3);
  asm volatile("s_waitcnt vmcnt(4)" ::: "memory");
  __builtin_amdgcn_s_barrier();
  __builtin_amdgcn_sched_barrier(0);

#define VMW asm volatile("s_waitcnt vmcnt(4)" ::: "memory")

  // Phase: [bf burst if LOADB] + 4 A-frag ds_read + 2 STG + [VMW] -> barrier
  //        -> setprio(1) 16 MFMA setprio(0). NO trailing barrier: next phase's
  //        reads may start under the SIMD-mate's MFMAs (the intended overlap).
#define PH(SA_, SB_, q_, LOADB_, S1_, S2_, VM_)                                               \
  {                                                                                           \
    if (LOADB_) {                                                                             \
      _Pragma("unroll") for (int ni = 0; ni < 4; ++ni) {                                      \
        bf[ni][0] = *(const v4i*)(SB_ + bro + ni * 2048 + pc0);                               \
        bf[ni][1] = *(const v4i*)(SB_ + bro + ni * 2048 + pc1);                               \
      }                                                                                       \
    }                                                                                         \
    v4i a00 = *(const v4i*)(SA_ + aro + (2 * (q_)) * 2048 + pc0);                             \
    v4i a01 = *(const v4i*)(SA_ + aro + (2 * (q_)) * 2048 + pc1);                             \
    v4i a10 = *(const v4i*)(SA_ + aro + (2 * (q_) + 1) * 2048 + pc0);                         \
    v4i a11 = *(const v4i*)(SA_ + aro + (2 * (q_) + 1) * 2048 + pc1);                         \
    S1_; S2_; VM_;                                                                            \
    __builtin_amdgcn_s_barrier();                                                             \
    __builtin_amdgcn_s_setprio(1);                                                           \
    _Pragma("unroll") for (int ni = 0; ni < 4; ++ni) {                                        \
      acc[2*(q_)][ni]   = __builtin_amdgcn_mfma_i32_16x16x64_i8(a00, bf[ni][0], acc[2*(q_)][ni], 0, 0, 0);     \
      acc[2*(q_)+1][ni] = __builtin_amdgcn_mfma_i32_16x16x64_i8(a10, bf[ni][0], acc[2*(q_)+1][ni], 0, 0, 0);   \
    }                                                                                         \
    _Pragma("unroll") for (int ni = 0; ni < 4; ++ni) {                                        \
      acc[2*(q_)][ni]   = __builtin_amdgcn_mfma_i32_16x16x64_i8(a01, bf[ni][1], acc[2*(q_)][ni], 0, 0, 0);     \
      acc[2*(q_)+1][ni] = __builtin_amdgcn_mfma_i32_16x16x64_i8(a11, bf[ni][1], acc[2*(q_)+1][ni], 0, 0, 0);   \
    }                                                                                         \
    __builtin_amdgcn_s_setprio(0);                                                           \
    __builtin_amdgcn_sched_barrier(0);                                                        \
  }

#pragma unroll 1
  for (int i = 0; i < NI; ++i) {
    v4i bf[4][2];
    const int t1 = 2 * i + 1;
    int t2 = 2 * i + 2; if (t2 >= NT) t2 -= NT;   // tail clamp: redundant but safe
    int t3 = 2 * i + 3; if (t3 >= NT) t3 -= NT;
    PH(sA0, sB0, 0, 1, STG(sA1, gA, t1, 0), STG(sA1, gA, t1, 1), (void)0);
    PH(sA0, sB0, 1, 0, STG(sA1, gA, t1, 2), STG(sA1, gA, t1, 3), (void)0);
    PH(sA0, sB0, 2, 0, STG(sB0, gB, t2, 0), STG(sB0, gB, t2, 1), (void)0);
    PH(sA0, sB0, 3, 0, STG(sB0, gB, t2, 2), STG(sB0, gB, t2, 3), VMW);
    PH(sA1, sB1, 0, 1, STG(sA0, gA, t2, 0), STG(sA0, gA, t2, 1), (void)0);
    PH(sA1, sB1, 1, 0, STG(sA0, gA, t2, 2), STG(sA0, gA, t2, 3), (void)0);
    PH(sA1, sB1, 2, 0, STG(sB1, gB, t3, 0), STG(sB1, gB, t3, 1), (void)0);
    PH(sA1, sB1, 3, 0, STG(sB1, gB, t3, 2), STG(sB1, gB, t3, 3), VMW);
  }
  // drain in-flight LDS writes before endpgm (LDS may be re-allocated)
  asm volatile("s_waitcnt vmcnt(0)" ::: "memory");

  // epilogue: C/D layout col=lane&15, row=(lane>>4)*4+reg (shape-determined).
  const int col0 = bn * 256 + wn + (lane & 15);
  const int row0 = bm * 256 + wm + ((lane >> 4) << 2);
  float scv[4], bsv[4];
#pragma unroll
  for (int ni = 0; ni < 4; ++ni) {
    scv[ni] = scale[col0 + ni * 16];
    bsv[ni] = bias[col0 + ni * 16];
  }
#pragma unroll
  for (int mi = 0; mi < 8; ++mi) {
#pragma unroll
    for (int r = 0; r < 4; ++r) {
      const int row = row0 + mi * 16 + r;
      const float as = ascale[row];
      float* crow = C + (size_t)row * Ndim;
#pragma unroll
      for (int ni = 0; ni < 4; ++ni)
        crow[col0 + ni * 16] = (float)acc[mi][ni][r] * as * scv[ni] + bsv[ni];
    }
  }
#undef PH
#undef VMW
#undef STG
}

// ---------- safety-net naive kernel (only if ws too small / odd shapes) -----
__global__ void naive_kernel(const float* __restrict__ A, const int* __restrict__ W,
                             const float* __restrict__ scale, const float* __restrict__ bias,
                             float* __restrict__ C, int Mdim, int Ndim, int Kdim) {
  int idx = blockIdx.x * blockDim.x + threadIdx.x;
  if (idx >= Mdim * Ndim) return;
  int row = idx / Ndim, col = idx % Ndim;
  const float* a = A + (size_t)row * Kdim;
  const int* w = W + (size_t)col * Kdim;
  float s = 0.f;
  for (int k = 0; k < Kdim; ++k) s += a[k] * (float)w[k];
  C[idx] = s * scale[col] + bias[col];
}

extern "C" void kernel_launch(void* const* d_in, const int* in_sizes, int n_in,
                              void* d_out, int out_size, void* d_ws, size_t ws_size,
                              hipStream_t stream) {
  const float* inp   = (const float*)d_in[0];
  const void*  w_raw = d_in[1];                 // int32 carrier (per harness) or int8
  const float* scale = (const float*)d_in[2];
  const float* bias  = (const float*)d_in[3];
  float* out = (float*)d_out;

  const int N = in_sizes[2];          // 4096 (D_OUT)
  const int K = in_sizes[1] / N;      // 4096 (D_IN)
  const int M = in_sizes[0] / K;      // 8192 (B*S)

  size_t needA = (size_t)M * K;              // int8 A
  size_t needW = (size_t)N * K;              // int8 W
  size_t needS = (size_t)M * sizeof(float);  // per-row scales
  size_t need  = needA + needW + needS + 16;

  const int nblk = (M / 256) * (N / 256);
  if (ws_size < need || (M % 256) || (N % 256) || (K != 4096) || (nblk % 8)) {
    int total = M * N;   // safety net — should not trigger for harness shapes
    naive_kernel<<<(total + 255) / 256, 256, 0, stream>>>(
        inp, (const int*)w_raw, scale, bias, out, M, N, K);
    return;
  }

  int8_t* Aq = (int8_t*)d_ws;
  int8_t* Wq = Aq + needA;
  float* ascale = (float*)(Wq + needW);

  // single fused prep launch: quant rows (blocks 0..M-1) + weight repack
  const int n4 = (N * K) / 4;
  const int repack_blocks = n4 / 256;
  prep_kernel<<<M + repack_blocks, 256, 0, stream>>>(inp, Aq, ascale, K, M,
                                                     w_raw, Wq);

  gemm_i8_8ph<<<nblk, 512, 0, stream>>>(Aq, Wq, ascale, scale, bias, out, M, N, K);
}